// Round 20
// baseline (57.558 us; speedup 1.0000x reference)
//
#include <hip/hip_runtime.h>

// 5-layer MLP [B,64]->32->12->8->6->2, fp32 in/out.
// Layer 0 on matrix cores, TRANSPOSED (D' = W0^T x x^T) via
// v_mfma_f32_32x32x16_bf16, 3-pass truncated-bf16 split; feature halves
// aligned with v_permlane32_swap_b32 (R15-proven epilogue, verbatim).
// R20 = R19 (register-direct staging, no LDS) with ISSUE-AFTER-CONSUME
// load placement: bank X of tile t+1 is issued immediately after bank X of
// tile t is consumed -> every bank has >=1500 cy of latency cover (vs 260
// for R19's bank B), loads spread evenly. WAR-safe by in-order issue.
// NT=8, grid=512 -> 2 blocks/CU (8 waves), single dispatch round.

typedef __attribute__((ext_vector_type(8))) short short8;
typedef __attribute__((ext_vector_type(16))) float f32x16;
typedef __attribute__((ext_vector_type(4))) unsigned uint4v;

#define BLOCK 256   // 4 independent waves/block
#define NT 8        // 64-row tiles per wave

__device__ __forceinline__ unsigned fbits(float x) {
    return __builtin_bit_cast(unsigned, x);
}
__device__ __forceinline__ float asf(unsigned u) {
    return __builtin_bit_cast(float, u);
}
// (hi16(ub)<<16) | hi16(ua)  -- one v_perm_b32
__device__ __forceinline__ unsigned packhi(unsigned ua, unsigned ub) {
    return __builtin_amdgcn_perm(ub, ua, 0x07060302u);
}
// 8 floats -> 8 truncated bf16 (element j = k-index j)
__device__ __forceinline__ short8 mk_hi(const float* f) {
    uint4v w;
#pragma unroll
    for (int t = 0; t < 4; ++t)
        w[t] = packhi(fbits(f[2 * t]), fbits(f[2 * t + 1]));
    return __builtin_bit_cast(short8, w);
}
// 8 floats -> bf16 of the truncation residuals
__device__ __forceinline__ short8 mk_lo(const float* f) {
    uint4v w;
#pragma unroll
    for (int t = 0; t < 4; ++t) {
        const float la = f[2 * t]     - asf(fbits(f[2 * t])     & 0xFFFF0000u);
        const float lb = f[2 * t + 1] - asf(fbits(f[2 * t + 1]) & 0xFFFF0000u);
        w[t] = packhi(fbits(la), fbits(lb));
    }
    return __builtin_bit_cast(short8, w);
}
#define MFMA(A, B, C) __builtin_amdgcn_mfma_f32_32x32x16_bf16(A, B, C, 0, 0, 0)

template <int IN, int OUT, bool RELU>
__device__ __forceinline__ void layer(const float* __restrict__ W,
                                      const float* __restrict__ b,
                                      const float* h_in, float* h_out) {
#pragma unroll
    for (int o = 0; o < OUT; ++o) h_out[o] = b[o];
#pragma unroll
    for (int i = 0; i < IN; ++i) {
        const float v = h_in[i];
#pragma unroll
        for (int o = 0; o < OUT; ++o)
            h_out[o] = fmaf(v, W[i * OUT + o], h_out[o]);   // uniform -> s_load
    }
    if (RELU) {
#pragma unroll
        for (int o = 0; o < OUT; ++o) h_out[o] = fmaxf(h_out[o], 0.0f);
    }
}

__global__ __launch_bounds__(BLOCK, 2) void mlp_kernel(
        const float* __restrict__ x,
        const float* __restrict__ W0, const float* __restrict__ b0,
        const float* __restrict__ W1, const float* __restrict__ b1,
        const float* __restrict__ W2, const float* __restrict__ b2,
        const float* __restrict__ W3, const float* __restrict__ b3,
        const float* __restrict__ W4, const float* __restrict__ b4,
        float* __restrict__ out, int nrows) {
    const int t = threadIdx.x;
    const int wv = t >> 6;
    const int lane = t & 63;

    const long long row0 = ((long long)blockIdx.x * 4 + wv) * (NT * 64);
    // Per-lane base: row lane&31, k-half (lane>>5)*32 bytes.
    const char* hbase = reinterpret_cast<const char*>(x + row0 * 64) +
                        (lane & 31) * 256 + (lane >> 5) * 32;

    const int hA = lane >> 5;
    const int colB = lane & 31;

    // --- W0^T fragments (A operand), built once, held in registers.
    //     k-step s: A[o = lane&31][k = 16s + 8*hA + j] = W0[k][o].
    short8 W0h_, W0l_, W1h_, W1l_, W2h_, W2l_, W3h_, W3l_;
    {
        float wf[8];
#define LOADW(s, BH, BL)                                                \
        {                                                               \
            _Pragma("unroll")                                           \
            for (int j = 0; j < 8; ++j)                                 \
                wf[j] = W0[((s) * 16 + 8 * hA + j) * 32 + colB];        \
            BH = mk_hi(wf);                                             \
            BL = mk_lo(wf);                                             \
        }
        LOADW(0, W0h_, W0l_)
        LOADW(1, W1h_, W1l_)
        LOADW(2, W2h_, W2l_)
        LOADW(3, W3h_, W3l_)
#undef LOADW
    }

    // Two register banks of 8 float4 (one 32-row half-tile each).
    float4 A0, A1, A2, A3, A4, A5, A6, A7;
    float4 B0, B1, B2, B3, B4, B5, B6, B7;

// Issue the 8 loads of half-tile at byte offset OFF into bank P.
// Offsets within a row: s*64 + q*16, s=0..3, q=0..1.
#define LOADH(OFF, P)                                                      \
    P##0 = *reinterpret_cast<const float4*>(hbase + (OFF) + 0);            \
    P##1 = *reinterpret_cast<const float4*>(hbase + (OFF) + 16);           \
    P##2 = *reinterpret_cast<const float4*>(hbase + (OFF) + 64);           \
    P##3 = *reinterpret_cast<const float4*>(hbase + (OFF) + 80);           \
    P##4 = *reinterpret_cast<const float4*>(hbase + (OFF) + 128);          \
    P##5 = *reinterpret_cast<const float4*>(hbase + (OFF) + 144);          \
    P##6 = *reinterpret_cast<const float4*>(hbase + (OFF) + 192);          \
    P##7 = *reinterpret_cast<const float4*>(hbase + (OFF) + 208);          \
    __builtin_amdgcn_sched_barrier(0);

// One K=16 step from bank registers Q0,Q1 (3-pass bf16 split).
#define KSTEP(Q0, Q1, WH, WL, ACC)                                         \
    {                                                                      \
        float f[8];                                                        \
        f[0] = Q0.x; f[1] = Q0.y; f[2] = Q0.z; f[3] = Q0.w;                \
        f[4] = Q1.x; f[5] = Q1.y; f[6] = Q1.z; f[7] = Q1.w;                \
        const short8 Xh = mk_hi(f), Xl = mk_lo(f);                         \
        ACC = MFMA(WH, Xh, ACC);                                           \
        ACC = MFMA(WL, Xh, ACC);                                           \
        ACC = MFMA(WH, Xl, ACC);                                           \
    }

    // Prologue: both half-tiles of tile 0.
    LOADH(0, A)
    LOADH(8192, B)

#pragma unroll 1
    for (int tt = 0; tt < NT; ++tt) {
        const long long noff = (long long)(tt + 1) * 16384;  // next tile base

        f32x16 accA, accB;   // D'[o][col]: accA cols = rows 0-31, accB 32-63
#pragma unroll
        for (int r = 0; r < 16; ++r) { accA[r] = 0.0f; accB[r] = 0.0f; }

        // Consume bank A, then immediately re-issue it for tile t+1
        // (old values already read at issue -> WAR-safe; >=1500 cy cover).
        KSTEP(A0, A1, W0h_, W0l_, accA)
        KSTEP(A2, A3, W1h_, W1l_, accA)
        KSTEP(A4, A5, W2h_, W2l_, accA)
        KSTEP(A6, A7, W3h_, W3l_, accA)
        if (tt + 1 < NT) {
            LOADH(noff, A)
        }

        // Consume bank B, then immediately re-issue it for tile t+1.
        KSTEP(B0, B1, W0h_, W0l_, accB)
        KSTEP(B2, B3, W1h_, W1l_, accB)
        KSTEP(B4, B5, W2h_, W2l_, accB)
        KSTEP(B6, B7, W3h_, W3l_, accB)
        if (tt + 1 < NT) {
            LOADH(noff + 8192, B)
        }

        // --- Align feature halves with permlane32_swap; bias+ReLU in-reg
        //     (R15-proven epilogue, verbatim).
        float xr[32];
#pragma unroll
        for (int reg = 0; reg < 16; ++reg) {
            float a = accA[reg];
            float b = accB[reg];
            asm("v_permlane32_swap_b32 %0, %1" : "+v"(a), "+v"(b));
            const int f0 = (reg & 3) + 8 * (reg >> 2);
            xr[f0]     = fmaxf(a + b0[f0],     0.0f);
            xr[f0 + 4] = fmaxf(b + b0[f0 + 4], 0.0f);
        }

        // Tail layers (16 loads of tile t+1 in flight during these).
        float h1[12], h2[8], h3[6], h4[2];
        layer<32, 12, true>(W1, b1, xr, h1);
        layer<12, 8, true>(W2, b2, h1, h2);
        layer<8, 6, true>(W3, b3, h2, h3);
        layer<6, 2, false>(W4, b4, h3, h4);

        reinterpret_cast<float2*>(out)[row0 + tt * 64 + lane] =
            make_float2(h4[0], h4[1]);
    }
#undef LOADH
#undef KSTEP
}

extern "C" void kernel_launch(void* const* d_in, const int* in_sizes, int n_in,
                              void* d_out, int out_size, void* d_ws, size_t ws_size,
                              hipStream_t stream) {
    const float* x  = (const float*)d_in[0];
    const float* W0 = (const float*)d_in[1];
    const float* b0 = (const float*)d_in[2];
    const float* W1 = (const float*)d_in[3];
    const float* b1 = (const float*)d_in[4];
    const float* W2 = (const float*)d_in[5];
    const float* b2 = (const float*)d_in[6];
    const float* W3 = (const float*)d_in[7];
    const float* b3 = (const float*)d_in[8];
    const float* W4 = (const float*)d_in[9];
    const float* b4 = (const float*)d_in[10];
    float* out = (float*)d_out;

    const int nrows = in_sizes[0] / 64;                 // 1,048,576
    const int rows_per_block = 4 * NT * 64;             // 2048
    const int grid = nrows / rows_per_block;            // 512 (exact)

    mlp_kernel<<<grid, BLOCK, 0, stream>>>(x, W0, b0, W1, b1, W2, b2,
                                           W3, b3, W4, b4, out, nrows);
}